// Round 8
// baseline (711.043 us; speedup 1.0000x reference)
//
#include <hip/hip_runtime.h>
#include <math.h>

// Boltzmann Gibbs sweep N=8192, single cooperative kernel.
// 16 blocks of BB=512. WG0 scans block b (8 x 64-step serial sub-scans);
// 255 workers compute panel dots vs private LDS state + gather coupling
// tiles + sub-7 strips; workers correct S with sub-dels 0..6 only; WG0
// self-applies the sub-7 correction (strip * del7) -> no worker round-trip
// on the block boundary. Diag m-tiles prefetched into LDS (wave1) so wave0
// holds a single m[64] (no spills). Chain step: decision = sign bit of
// g = sum - th via readlane(hi) + SALU select (no f64 cmp in the chain).
// Cross-WG payloads: agent-scope relaxed (sc1) stores; ordering = vmcnt
// drain at __syncthreads + relaxed flag store. No wbl2/inv on the path.
// Decision: u <= sigmoid(s/T) <=> s >= T*log(u/(1-u)); thr fp64,
// POSITION-indexed (lax.scan zips (perm, rand_u)); clamp/state UNIT-indexed.
// All sums fp64; every correction product w*delta is exact in fp32.

#define NN 8192
#define BB 512
#define NBLK 16
#define SUB 64
#define NSUB 8
#define NWG 256
#define NWORK 255
#define TPB 512
#define MAXR 3
#define MSTR 68                      // padded LDS row stride (floats)
#define MBUFW (SUB * MSTR)           // one m-tile buffer (floats)

typedef unsigned int u32;
typedef unsigned long long u64;

__global__ void k_init(u32* flags, int n) {
  int i = blockIdx.x * blockDim.x + threadIdx.x;
  for (; i < n; i += gridDim.x * blockDim.x) flags[i] = 0;
}

__device__ __forceinline__ u32 ld_rlx(const u32* p) {
  return __hip_atomic_load(p, __ATOMIC_RELAXED, __HIP_MEMORY_SCOPE_AGENT);
}
__device__ __forceinline__ void st_rlx(u32* p, u32 v) {
  __hip_atomic_store(p, v, __ATOMIC_RELAXED, __HIP_MEMORY_SCOPE_AGENT);
}
__device__ __forceinline__ float ldf_rlx(const float* p) {
  return __hip_atomic_load(p, __ATOMIC_RELAXED, __HIP_MEMORY_SCOPE_AGENT);
}
__device__ __forceinline__ void stf_rlx(float* p, float v) {
  __hip_atomic_store(p, v, __ATOMIC_RELAXED, __HIP_MEMORY_SCOPE_AGENT);
}
__device__ __forceinline__ double ldd_rlx(const double* p) {
  return __hip_atomic_load(p, __ATOMIC_RELAXED, __HIP_MEMORY_SCOPE_AGENT);
}
__device__ __forceinline__ void std_rlx(double* p, double v) {
  __hip_atomic_store(p, v, __ATOMIC_RELAXED, __HIP_MEMORY_SCOPE_AGENT);
}
__device__ __forceinline__ u64 ldq_rlx(const u64* p) {
  return __hip_atomic_load(p, __ATOMIC_RELAXED, __HIP_MEMORY_SCOPE_AGENT);
}

__global__ __launch_bounds__(TPB) void k_gibbs(
    const float* __restrict__ w, const float* __restrict__ init,
    const float* __restrict__ clampv, const float* __restrict__ Tp,
    const int* __restrict__ perm, const float* __restrict__ urand,
    float* __restrict__ dout,
    double* __restrict__ thrG, double* __restrict__ S,
    float* __restrict__ d1G, float* __restrict__ d0G,
    float* __restrict__ oldG, float* __restrict__ delG,
    float* __restrict__ stripG, float* __restrict__ tileD,
    u32* subFlag, u32* ack) {
  // manual LDS union: WG0 uses ~53 KB, workers use ~33 KB
  __shared__ double poolD[55296 / 8];
  const int wg = blockIdx.x, tid = threadIdx.x;
  const int wv = tid >> 6, lane = tid & 63;

  if (wg == 0) {
    double* sumsL = poolD;                                   // 512 f64
    double* thrL  = poolD + BB;                              // 512 f64
    float*  d1L   = (float*)(poolD + 2 * BB);                // 512 f32
    float*  d0L   = d1L + BB;
    float*  delL  = d0L + BB;
    float*  oldL  = delL + BB;
    int*    uL    = (int*)(oldL + BB);
    float*  mbuf  = (float*)(uL + BB);                       // 2 * 64 * 68 f32

    // ---- prologue: tables for all 8192 positions (workers busy with dots) ----
    double T = (double)Tp[0];
    for (int i = tid; i < NN; i += TPB) {
      int unit = perm[i];
      double uu = (double)urand[i];
      std_rlx(&thrG[i], T * log(uu / (1.0 - uu)));   // u==0 -> -inf -> always 1
      float old = init[unit];
      bool cl = (clampv[unit] != 0.0f);
      stf_rlx(&d1G[i], cl ? 0.0f : (1.0f - old));
      stf_rlx(&d0G[i], cl ? 0.0f : (0.0f - old));
      stf_rlx(&oldG[i], old);
    }
    __syncthreads();
    // wait acks(0): S[0] raw dots + tile 0 ready
    {
      const u32* slots = ack;
      for (;;) {
        int ok = 1;
        if (tid < NWORK) ok = (ld_rlx(&slots[tid]) != 0u);
        if (__syncthreads_and(ok)) break;
        __builtin_amdgcn_s_sleep(1);
      }
    }
    sumsL[tid] = ldd_rlx(&S[tid]);
    thrL[tid] = ldd_rlx(&thrG[tid]);
    d1L[tid] = ldf_rlx(&d1G[tid]);
    d0L[tid] = ldf_rlx(&d0G[tid]);
    oldL[tid] = ldf_rlx(&oldG[tid]);
    uL[tid] = perm[tid];
    if (tid >= 448) {                      // wave7: diag(0) of block 0 -> mbuf[0]
      int l = tid - 448;
      const float4* src = (const float4*)(tileD + (size_t)l * BB);
      float4* dst = (float4*)(mbuf + l * MSTR);
#pragma unroll
      for (int j = 0; j < 16; ++j) dst[j] = src[j];
    }
    __syncthreads();

    float4 nv0, nv1, nv2, nv3;             // near-strip prefetch regs (waves 4-7)
    for (int b = 0; b < NBLK; ++b) {
      const bool pub = (b + 1 < NBLK);
      const float* tb = tileD + (size_t)b * BB * BB;

      for (int t8 = 0; t8 < NSUB; ++t8) {
        int o = t8 * SUB;
        float m[SUB];
        // ---------------- A section ----------------
        if (t8 > 0 && pub && tid == 0) st_rlx(&subFlag[b * NSUB + t8 - 1], 1u);
        if (tid < SUB) {
          // m-tile from LDS (prefetched) -> regs
          const float4* mr = (const float4*)(mbuf + (t8 & 1) * MBUFW + tid * MSTR);
#pragma unroll
          for (int j = 0; j < 16; ++j) {
            float4 v = mr[j];
            m[4*j] = v.x; m[4*j+1] = v.y; m[4*j+2] = v.z; m[4*j+3] = v.w;
          }
        } else if (t8 > 0 && tid >= 256) {
          // near-pass: apply del(t8-1) to the 64 rows about to be scanned
          int t = tid - 256, g_ = t >> 2, q = t & 3;
          int rrow = o + g_;
          int c0 = (t8 - 1) * SUB + q * 16;
          double p_ =
              (double)(nv0.x * delL[c0])    + (double)(nv0.y * delL[c0+1]) +
              (double)(nv0.z * delL[c0+2])  + (double)(nv0.w * delL[c0+3]) +
              (double)(nv1.x * delL[c0+4])  + (double)(nv1.y * delL[c0+5]) +
              (double)(nv1.z * delL[c0+6])  + (double)(nv1.w * delL[c0+7]);
          p_ +=
              (double)(nv2.x * delL[c0+8])  + (double)(nv2.y * delL[c0+9]) +
              (double)(nv2.z * delL[c0+10]) + (double)(nv2.w * delL[c0+11]) +
              (double)(nv3.x * delL[c0+12]) + (double)(nv3.y * delL[c0+13]) +
              (double)(nv3.z * delL[c0+14]) + (double)(nv3.w * delL[c0+15]);
          p_ += __shfl_down(p_, 2, 4);
          p_ += __shfl_down(p_, 1, 4);
          if (q == 0) sumsL[rrow] += p_;
        }
        __syncthreads();
        // ---------------- B section ----------------
        if (tid < SUB) {
          // serial 64-step sub-scan: sign-bit decision chain
          int row = o + tid;
          double g = sumsL[row] - thrL[row];
          float d1v = d1L[row], d0v = d0L[row];
          u64 xb = 0ull;
          __builtin_amdgcn_s_setprio(3);
#pragma unroll
          for (int s = 0; s < SUB; ++s) {
            int hi = __builtin_amdgcn_readlane(
                (int)(__double_as_longlong(g) >> 32), s);
            int x = (hi >= 0) ? 1 : 0;
            int a1 = __builtin_amdgcn_readlane((int)__float_as_uint(d1v), s);
            int a0 = __builtin_amdgcn_readlane((int)__float_as_uint(d0v), s);
            float sd = __uint_as_float((u32)(x ? a1 : a0));
            g += (double)(m[s] * sd);          // exact fp32 product
            xb |= ((u64)x) << s;
          }
          __builtin_amdgcn_s_setprio(0);
          float mydel = ((xb >> tid) & 1ull) ? d1v : d0v;
          delL[row] = mydel;
          if (pub) stf_rlx(&delG[b * BB + row], mydel);
        } else if (tid < 128) {
          // wave1: prefetch diag(t8+1) -> mbuf[(t8+1)&1]
          if (t8 < NSUB - 1) {
            int l = tid - 64, o2 = (t8 + 1) * SUB;
            const float4* src = (const float4*)(tb + (size_t)(o2 + l) * BB + o2);
            float4* dst = (float4*)(mbuf + ((t8 + 1) & 1) * MBUFW + l * MSTR);
#pragma unroll
            for (int j = 0; j < 16; ++j) dst[j] = src[j];
          }
        } else {
          if (t8 < NSUB - 1 && tid >= 256) {
            // prefetch near-strip: rows sub(t8+1), cols sub(t8)
            int t = tid - 256;
            const float4* pr = (const float4*)(
                tb + (size_t)((t8 + 1) * SUB + (t >> 2)) * BB + o + (t & 3) * 16);
            nv0 = pr[0]; nv1 = pr[1]; nv2 = pr[2]; nv3 = pr[3];
          }
          if (t8 > 0) {
            // far-pass: apply del(t8-1) to rows beyond sub t8 (waves 2-7)
            for (int r = (t8 + 1) * SUB + (tid - 128); r < BB; r += 384) {
              int c0 = (t8 - 1) * SUB;
              const float4* mr3 = (const float4*)(tb + (size_t)r * BB + c0);
              double acc = sumsL[r];
#pragma unroll
              for (int j = 0; j < SUB / 4; ++j) {
                float4 v = mr3[j];
                acc += (double)(v.x * delL[c0+4*j])   + (double)(v.y * delL[c0+4*j+1]) +
                       (double)(v.z * delL[c0+4*j+2]) + (double)(v.w * delL[c0+4*j+3]);
              }
              sumsL[r] = acc;
            }
          }
        }
        __syncthreads();                     // drains delG / mbuf stores
      }
      // ---------------- post-block ----------------
      if (pub && tid == 0) st_rlx(&subFlag[b * NSUB + NSUB - 1], 1u);
      dout[uL[tid]] = oldL[tid] + delL[tid];   // exact {0,1} / clamped init
      if (pub) {
        // wait acks(b+1): S[b+1] (sub0-6 corrected) + tile + strip ready
        {
          const u32* slots = ack + (size_t)(b + 1) * NWORK;
          for (;;) {
            int ok = 1;
            if (tid < NWORK) ok = (ld_rlx(&slots[tid]) != 0u);
            if (__syncthreads_and(ok)) break;
            __builtin_amdgcn_s_sleep(1);
          }
        }
        // self-correction: sumsL = S[b+1] + strip * del7   (one row per thread)
        {
          double acc = ldd_rlx(&S[(size_t)(b + 1) * BB + tid]);
          const u64* sp = (const u64*)(stripG + ((size_t)(b + 1) * BB + tid) * SUB);
#pragma unroll
          for (int k = 0; k < SUB / 2; ++k) {
            u64 q = ldq_rlx(&sp[k]);
            float f0 = __uint_as_float((u32)q);
            float f1 = __uint_as_float((u32)(q >> 32));
            acc += (double)(f0 * delL[448 + 2 * k]) +
                   (double)(f1 * delL[448 + 2 * k + 1]);
          }
          sumsL[tid] = acc;
        }
        // tables for block b+1
        {
          int pos = (b + 1) * BB + tid;
          thrL[tid] = ldd_rlx(&thrG[pos]);
          d1L[tid] = ldf_rlx(&d1G[pos]);
          d0L[tid] = ldf_rlx(&d0G[pos]);
          oldL[tid] = ldf_rlx(&oldG[pos]);
          uL[tid] = perm[pos];
        }
        if (tid >= 448) {                    // wave7: diag(0) of b+1 -> mbuf[0]
          int l = tid - 448;
          const float4* src = (const float4*)(
              tileD + (size_t)(b + 1) * BB * BB + (size_t)l * BB);
          float4* dst = (float4*)(mbuf + l * MSTR);
#pragma unroll
          for (int j = 0; j < 16; ++j) dst[j] = src[j];
        }
        __syncthreads();
      }
    }
  } else {
    // ================= workers =================
    float* stateL = (float*)poolD;                           // 32 KB
    double* redW = (double*)((char*)poolD + 32768);          // [8][MAXR]
    const int iw = wg - 1;
    const int r0 = (iw * BB) / NWORK, r1 = ((iw + 1) * BB) / NWORK;
    const int cnt = r1 - r0;                                 // 2..3
    for (int i = tid; i < NN; i += TPB) stateL[i] = init[i];
    __syncthreads();

    for (int p = 0; p < NBLK; ++p) {
      // deferred sub-7 state update of block p-2
      if (p >= 2) {
        const u32* f = &subFlag[(p - 2) * NSUB + NSUB - 1];
        if (tid == 0) { while (ld_rlx(f) == 0u) __builtin_amdgcn_s_sleep(1); }
        __syncthreads();
        if (tid < SUB)
          stateL[perm[(p - 2) * BB + 7 * SUB + tid]] +=
              ldf_rlx(&delG[(p - 2) * BB + 7 * SUB + tid]);
        __syncthreads();
      }
      int pc = perm[p * BB + tid];                 // tile col units
      float g[NSUB - 1];                           // sub 0..6 corr strip
      float* tbp = tileD + (size_t)p * BB * BB;

      for (int ri = 0; ri < cnt; ++ri) {
        int unit = perm[p * BB + r0 + ri];
        const float* wrow = w + (size_t)unit * NN;
        const float4* wr4 = (const float4*)wrow;
        const float4* st4 = (const float4*)stateL;
        double acc = 0.0;
#pragma unroll
        for (int k = 0; k < NN / (4 * TPB); ++k) {  // 4 iters
          float4 a = wr4[tid + k * TPB];
          float4 s = st4[tid + k * TPB];
          acc += (double)(a.x * s.x) + (double)(a.y * s.y) +
                 (double)(a.z * s.z) + (double)(a.w * s.w);
        }
        for (int o = 32; o > 0; o >>= 1) acc += __shfl_down(acc, o, 64);
        if (lane == 0) redW[wv * MAXR + ri] = acc;
        stf_rlx(&tbp[(size_t)(r0 + ri) * BB + tid], wrow[pc]);   // tile row
        if (p > 0 && wv == ri) {
#pragma unroll
          for (int t8 = 0; t8 < NSUB - 1; ++t8)
            g[t8] = wrow[perm[(p - 1) * BB + t8 * SUB + lane]];
          // sub-7 strip -> global (WG0 self-corrects with it)
          stf_rlx(&stripG[((size_t)p * BB + r0 + ri) * SUB + lane],
                  wrow[perm[(p - 1) * BB + 7 * SUB + lane]]);
        }
      }
      __syncthreads();
      double Sr = 0.0;
      if (wv < cnt) {
#pragma unroll
        for (int k = 0; k < TPB / 64; ++k) Sr += redW[k * MAXR + wv];
      }
      if (p > 0) {
        // incremental in-register corrections, sub-dels 0..6 only
        double crr = 0.0;
#pragma unroll
        for (int t8 = 0; t8 < NSUB - 1; ++t8) {
          const u32* f = &subFlag[(p - 1) * NSUB + t8];
          if (tid == 0) { while (ld_rlx(f) == 0u) __builtin_amdgcn_s_sleep(1); }
          __syncthreads();
          float dl = ldf_rlx(&delG[(p - 1) * BB + t8 * SUB + lane]);
          if (wv < cnt) crr += (double)(g[t8] * dl);       // exact product
          if (tid < SUB) stateL[perm[(p - 1) * BB + t8 * SUB + tid]] += dl;
        }
        for (int o = 32; o > 0; o >>= 1) crr += __shfl_down(crr, o, 64);
        Sr += crr;
      }
      if (wv < cnt && lane == 0) std_rlx(&S[(size_t)p * BB + r0 + wv], Sr);
      __syncthreads();                     // drain all sc1 stores (vmcnt)
      if (tid == 0) st_rlx(&ack[(size_t)p * NWORK + iw], 1u);
    }
  }
}

extern "C" void kernel_launch(void* const* d_in, const int* in_sizes, int n_in,
                              void* d_out, int out_size, void* d_ws, size_t ws_size,
                              hipStream_t stream) {
  const float* w      = (const float*)d_in[0];
  const float* init   = (const float*)d_in[1];
  const float* clampv = (const float*)d_in[2];
  const float* Tp     = (const float*)d_in[3];
  const int*   perm   = (const int*)d_in[4];
  const float* urand  = (const float*)d_in[5];
  float* dout = (float*)d_out;

  double* thrG = (double*)d_ws;                         // NN
  double* S    = thrG + NN;                             // NN
  float* d1G   = (float*)(S + NN);                      // NN
  float* d0G   = d1G + NN;                              // NN
  float* oldG  = d0G + NN;                              // NN
  float* delG  = oldG + NN;                             // NN
  float* stripG = delG + NN;                            // NBLK*BB*SUB (2 MB)
  float* tileD = stripG + (size_t)NBLK * BB * SUB;      // NBLK*BB*BB (16 MB)
  u32* subFlag = (u32*)(tileD + (size_t)NBLK * BB * BB);   // NBLK*NSUB
  u32* ack     = subFlag + NBLK * NSUB;                    // NBLK*NWORK

  int nflags = NBLK * NSUB + NBLK * NWORK;
  k_init<<<8, 256, 0, stream>>>(subFlag, nflags);

  void* args[] = {(void*)&w, (void*)&init, (void*)&clampv, (void*)&Tp,
                  (void*)&perm, (void*)&urand, (void*)&dout,
                  (void*)&thrG, (void*)&S, (void*)&d1G, (void*)&d0G,
                  (void*)&oldG, (void*)&delG, (void*)&stripG, (void*)&tileD,
                  (void*)&subFlag, (void*)&ack};
  hipLaunchCooperativeKernel((const void*)k_gibbs, dim3(NWG), dim3(TPB),
                             args, 0, stream);
}

// Round 9
// 589.408 us; speedup vs baseline: 1.2064x; 1.2064x over previous
//
#include <hip/hip_runtime.h>
#include <math.h>

// Boltzmann Gibbs sweep N=8192, single cooperative kernel.
// 16 blocks of BB=512. WG0 scans block b (8 x 64-step serial sub-scans);
// 255 workers compute panel dots vs private LDS state + gather coupling
// tiles; at block end WG0 publishes all 512 deltas ONCE (single flag),
// workers do a rank-512 in-register correction of S[b+1] and ack.
// No global stores inside WG0's phase loop -> phase barriers drain nothing.
// Chain: decision = sign bit of g = sum - th; per step one readlane +
// scalar cselect from ballot-precomputed {+1,0,-1} masks (d1 in {0,1},
// d0 in {0,-1}) -> no per-step d1/d0 broadcasts, no spills (single m[64]).
// Cross-WG payloads (S, delG) via agent-scope relaxed sc1 atomics; tiles
// written sc1, read with plain loads (fresh lines -> L3; deterministic).
// Decision: u <= sigmoid(s/T) <=> s >= T*log(u/(1-u)); thr fp64,
// POSITION-indexed (lax.scan zips (perm, rand_u)); clamp/state UNIT-indexed.
// All sums fp64; every correction product w*delta is exact in fp32.

#define NN 8192
#define BB 512
#define NBLK 16
#define SUB 64
#define NSUB 8
#define NWG 256
#define NWORK 255
#define TPB 512
#define MAXR 3
#define MSTR 68                      // padded LDS m-row stride (floats)
#define MBUFW (SUB * MSTR)

typedef unsigned int u32;
typedef unsigned long long u64;

__global__ void k_init(u32* flags, int n) {
  int i = blockIdx.x * blockDim.x + threadIdx.x;
  for (; i < n; i += gridDim.x * blockDim.x) flags[i] = 0;
}

__device__ __forceinline__ u32 ld_rlx(const u32* p) {
  return __hip_atomic_load(p, __ATOMIC_RELAXED, __HIP_MEMORY_SCOPE_AGENT);
}
__device__ __forceinline__ void st_rlx(u32* p, u32 v) {
  __hip_atomic_store(p, v, __ATOMIC_RELAXED, __HIP_MEMORY_SCOPE_AGENT);
}
__device__ __forceinline__ float ldf_rlx(const float* p) {
  return __hip_atomic_load(p, __ATOMIC_RELAXED, __HIP_MEMORY_SCOPE_AGENT);
}
__device__ __forceinline__ void stf_rlx(float* p, float v) {
  __hip_atomic_store(p, v, __ATOMIC_RELAXED, __HIP_MEMORY_SCOPE_AGENT);
}
__device__ __forceinline__ double ldd_rlx(const double* p) {
  return __hip_atomic_load(p, __ATOMIC_RELAXED, __HIP_MEMORY_SCOPE_AGENT);
}
__device__ __forceinline__ void std_rlx(double* p, double v) {
  __hip_atomic_store(p, v, __ATOMIC_RELAXED, __HIP_MEMORY_SCOPE_AGENT);
}

__global__ __launch_bounds__(TPB) void k_gibbs(
    const float* __restrict__ w, const float* __restrict__ init,
    const float* __restrict__ clampv, const float* __restrict__ Tp,
    const int* __restrict__ perm, const float* __restrict__ urand,
    float* __restrict__ dout, double* __restrict__ S,
    float* __restrict__ delG, float* __restrict__ tileD,
    u32* delReady, u32* ack) {
  __shared__ double poolD[55296 / 8];   // union: WG0 ~53 KB, workers ~33 KB
  const int wg = blockIdx.x, tid = threadIdx.x;
  const int wv = tid >> 6, lane = tid & 63;

  if (wg == 0) {
    double* sumsL = poolD;                                   // 512 f64
    double* thrL  = poolD + BB;                              // 512 f64
    float*  d1L   = (float*)(poolD + 2 * BB);                // 512 f32 x4
    float*  d0L   = d1L + BB;
    float*  delL  = d0L + BB;
    float*  oldL  = delL + BB;
    int*    uL    = (int*)(oldL + BB);                       // 512 i32
    float*  mbuf  = (float*)(uL + BB);                       // 2*64*68 f32

    double T = (double)Tp[0];
    for (int b = 0; b < NBLK; ++b) {
      const bool pub = (b + 1 < NBLK);
      // ---- per-block tables (before the ack wait; overlapped) ----
      int pos = b * BB + tid;                    // TPB == BB
      int unit = perm[pos];
      double uu = (double)urand[pos];
      thrL[tid] = T * log(uu / (1.0 - uu));      // u==0 -> -inf -> always 1
      float old = init[unit];
      bool cl = (clampv[unit] != 0.0f);
      d1L[tid] = cl ? 0.0f : (1.0f - old);       // in {0,1}
      d0L[tid] = cl ? 0.0f : (0.0f - old);       // in {0,-1}
      oldL[tid] = old;
      uL[tid] = unit;
      // ---- wait: all workers acked block b (S[b] corrected, tile b in L3) ----
      {
        const u32* slots = ack + (size_t)b * NWORK;
        for (;;) {
          int ok = 1;
          if (tid < NWORK) ok = (ld_rlx(&slots[tid]) != 0u);
          if (__syncthreads_and(ok)) break;
          __builtin_amdgcn_s_sleep(1);
        }
      }
      sumsL[tid] = ldd_rlx(&S[(size_t)b * BB + tid]);
      if (tid >= 448) {                  // wave7: diag(0) of block b -> mbuf[0]
        int l = tid - 448;
        const float4* src = (const float4*)(tileD + (size_t)b * BB * BB + (size_t)l * BB);
        float4* dst = (float4*)(mbuf + l * MSTR);
#pragma unroll
        for (int j = 0; j < 16; ++j) dst[j] = src[j];
      }
      __syncthreads();
      const float* tb = tileD + (size_t)b * BB * BB;
      float4 nv0, nv1, nv2, nv3;         // near-strip prefetch regs (waves 4-7)

      for (int t8 = 0; t8 < NSUB; ++t8) {
        int o = t8 * SUB;
        float m[SUB];
        // ---------------- A section (no global stores anywhere) ----------------
        if (tid < SUB) {
          const float4* mr = (const float4*)(mbuf + (t8 & 1) * MBUFW + tid * MSTR);
#pragma unroll
          for (int j = 0; j < 16; ++j) {
            float4 v = mr[j];
            m[4*j] = v.x; m[4*j+1] = v.y; m[4*j+2] = v.z; m[4*j+3] = v.w;
          }
        } else if (t8 > 0 && tid >= 256) {
          // near-pass: apply del(t8-1) to the 64 rows about to be scanned
          int t = tid - 256, g_ = t >> 2, q = t & 3;
          int rrow = o + g_;
          int c0 = (t8 - 1) * SUB + q * 16;
          double p_ =
              (double)(nv0.x * delL[c0])    + (double)(nv0.y * delL[c0+1]) +
              (double)(nv0.z * delL[c0+2])  + (double)(nv0.w * delL[c0+3]) +
              (double)(nv1.x * delL[c0+4])  + (double)(nv1.y * delL[c0+5]) +
              (double)(nv1.z * delL[c0+6])  + (double)(nv1.w * delL[c0+7]);
          p_ +=
              (double)(nv2.x * delL[c0+8])  + (double)(nv2.y * delL[c0+9]) +
              (double)(nv2.z * delL[c0+10]) + (double)(nv2.w * delL[c0+11]) +
              (double)(nv3.x * delL[c0+12]) + (double)(nv3.y * delL[c0+13]) +
              (double)(nv3.z * delL[c0+14]) + (double)(nv3.w * delL[c0+15]);
          p_ += __shfl_down(p_, 2, 4);
          p_ += __shfl_down(p_, 1, 4);
          if (q == 0) sumsL[rrow] += p_;
        }
        __syncthreads();
        // ---------------- B section ----------------
        if (tid < SUB) {
          float d1v = d1L[o + tid], d0v = d0L[o + tid];
          u64 P1 = __ballot(d1v != 0.0f);        // accept -> +1
          u64 M0 = __ballot(d0v != 0.0f);        // reject -> -1
          double g = sumsL[o + tid] - thrL[o + tid];
          u64 xb = 0ull;
          __builtin_amdgcn_s_setprio(3);
#pragma unroll
          for (int s = 0; s < SUB; ++s) {
            u32 t1 = ((P1 >> s) & 1ull) ? 0x3f800000u : 0u;   // off-path
            u32 t0 = ((M0 >> s) & 1ull) ? 0xbf800000u : 0u;   // off-path
            int hi = __builtin_amdgcn_readlane(
                (int)(__double_as_longlong(g) >> 32), s);
            float sdf = __uint_as_float((hi >= 0) ? t1 : t0);
            g += (double)(m[s] * sdf);           // exact fp32 product
            xb |= ((u64)(hi >= 0 ? 1 : 0)) << s;
          }
          __builtin_amdgcn_s_setprio(0);
          delL[o + tid] = ((xb >> tid) & 1ull) ? d1v : d0v;
        } else if (tid < 128) {
          // wave1: prefetch diag(t8+1) global -> mbuf[(t8+1)&1]
          if (t8 < NSUB - 1) {
            int l = tid - 64, o2 = (t8 + 1) * SUB;
            const float4* src = (const float4*)(tb + (size_t)(o2 + l) * BB + o2);
            float4* dst = (float4*)(mbuf + ((t8 + 1) & 1) * MBUFW + l * MSTR);
#pragma unroll
            for (int j = 0; j < 16; ++j) dst[j] = src[j];
          }
        } else {
          if (t8 < NSUB - 1 && tid >= 256) {
            // prefetch near-strip: rows sub(t8+1), cols sub(t8)
            int t = tid - 256;
            const float4* pr = (const float4*)(
                tb + (size_t)((t8 + 1) * SUB + (t >> 2)) * BB + o + (t & 3) * 16);
            nv0 = pr[0]; nv1 = pr[1]; nv2 = pr[2]; nv3 = pr[3];
          }
          if (t8 > 0) {
            // far-pass: apply del(t8-1) to rows beyond sub t8 (waves 2-7)
            for (int r = (t8 + 1) * SUB + (tid - 128); r < BB; r += 384) {
              int c0 = (t8 - 1) * SUB;
              const float4* mr3 = (const float4*)(tb + (size_t)r * BB + c0);
              double acc = sumsL[r];
#pragma unroll
              for (int j = 0; j < SUB / 4; ++j) {
                float4 v = mr3[j];
                acc += (double)(v.x * delL[c0+4*j])   + (double)(v.y * delL[c0+4*j+1]) +
                       (double)(v.z * delL[c0+4*j+2]) + (double)(v.w * delL[c0+4*j+3]);
              }
              sumsL[r] = acc;
            }
          }
        }
        __syncthreads();                 // lgkm-only drain (no global stores)
      }
      // ---------------- post-block: single batched publish ----------------
      if (pub) {
        stf_rlx(&delG[b * BB + tid], delL[tid]);   // 2 KB, coalesced
        __syncthreads();                           // one store-drain per block
        if (tid == 0) st_rlx(&delReady[b], 1u);
      }
      dout[uL[tid]] = oldL[tid] + delL[tid];       // exact {0,1} / clamped init
    }
  } else {
    // ================= workers =================
    float* stateL = (float*)poolD;                           // 32 KB
    double* redW = (double*)((char*)poolD + 32768);          // [8][MAXR]
    const int iw = wg - 1;
    const int r0 = (iw * BB) / NWORK, r1 = ((iw + 1) * BB) / NWORK;
    const int cnt = r1 - r0;                                 // 2..3
    for (int i = tid; i < NN; i += TPB) stateL[i] = init[i];
    __syncthreads();

    for (int p = 0; p < NBLK; ++p) {
      int pc = perm[p * BB + tid];                 // tile col units
      float g[NSUB];                               // my row's corr strip
      float* tbp = tileD + (size_t)p * BB * BB;

      for (int ri = 0; ri < cnt; ++ri) {
        int unit = perm[p * BB + r0 + ri];
        const float* wrow = w + (size_t)unit * NN;
        const float4* wr4 = (const float4*)wrow;
        const float4* st4 = (const float4*)stateL;
        double acc = 0.0;
#pragma unroll
        for (int k = 0; k < NN / (4 * TPB); ++k) {  // 4 iters
          float4 a = wr4[tid + k * TPB];
          float4 s = st4[tid + k * TPB];
          acc += (double)(a.x * s.x) + (double)(a.y * s.y) +
                 (double)(a.z * s.z) + (double)(a.w * s.w);
        }
        for (int o = 32; o > 0; o >>= 1) acc += __shfl_down(acc, o, 64);
        if (lane == 0) redW[wv * MAXR + ri] = acc;
        stf_rlx(&tbp[(size_t)(r0 + ri) * BB + tid], wrow[pc]);   // tile row
        if (p > 0 && wv == ri) {                    // strip vs block p-1 (L1-hot)
#pragma unroll
          for (int t8 = 0; t8 < NSUB; ++t8)
            g[t8] = wrow[perm[(p - 1) * BB + t8 * SUB + lane]];
        }
      }
      __syncthreads();
      double Sr = 0.0;
      if (wv < cnt) {
#pragma unroll
        for (int k = 0; k < TPB / 64; ++k) Sr += redW[k * MAXR + wv];
      }
      if (p > 0) {
        // single wait: all 512 dels of block p-1 ready
        if (tid == 0) {
          while (ld_rlx(&delReady[p - 1]) == 0u) __builtin_amdgcn_s_sleep(1);
        }
        __syncthreads();
        double crr = 0.0;
        if (wv < cnt) {
#pragma unroll
          for (int t8 = 0; t8 < NSUB; ++t8)
            crr += (double)(g[t8] * ldf_rlx(&delG[(p - 1) * BB + t8 * SUB + lane]));
          for (int o = 32; o > 0; o >>= 1) crr += __shfl_down(crr, o, 64);
          Sr += crr;
        }
      }
      if (wv < cnt && lane == 0) std_rlx(&S[(size_t)p * BB + r0 + wv], Sr);
      __syncthreads();                    // drain S (and tile) sc1 stores
      if (tid == 0) st_rlx(&ack[(size_t)p * NWORK + iw], 1u);
      // advance private state with block p-1's dels (one per thread)
      if (p > 0) {
        float dl = ldf_rlx(&delG[(p - 1) * BB + tid]);
        stateL[perm[(p - 1) * BB + tid]] += dl;
      }
      __syncthreads();
    }
  }
}

extern "C" void kernel_launch(void* const* d_in, const int* in_sizes, int n_in,
                              void* d_out, int out_size, void* d_ws, size_t ws_size,
                              hipStream_t stream) {
  const float* w      = (const float*)d_in[0];
  const float* init   = (const float*)d_in[1];
  const float* clampv = (const float*)d_in[2];
  const float* Tp     = (const float*)d_in[3];
  const int*   perm   = (const int*)d_in[4];
  const float* urand  = (const float*)d_in[5];
  float* dout = (float*)d_out;

  double* S    = (double*)d_ws;                         // NBLK*BB doubles
  float* delG  = (float*)(S + (size_t)NBLK * BB);       // NN floats
  float* tileD = delG + NN;                             // NBLK*BB*BB (16 MB)
  u32* delReady = (u32*)(tileD + (size_t)NBLK * BB * BB);  // NBLK
  u32* ack      = delReady + NBLK;                         // NBLK*NWORK

  int nflags = NBLK + NBLK * NWORK;
  k_init<<<8, 256, 0, stream>>>(delReady, nflags);

  void* args[] = {(void*)&w, (void*)&init, (void*)&clampv, (void*)&Tp,
                  (void*)&perm, (void*)&urand, (void*)&dout,
                  (void*)&S, (void*)&delG, (void*)&tileD,
                  (void*)&delReady, (void*)&ack};
  hipLaunchCooperativeKernel((const void*)k_gibbs, dim3(NWG), dim3(TPB),
                             args, 0, stream);
}